// Round 1
// baseline (11347.483 us; speedup 1.0000x reference)
//
#include <hip/hip_runtime.h>
#include <hip/hip_bf16.h>
#include <math.h>

#define Bn 128
#define Pn 196
#define ENCn 2048
#define Dn 512
#define An 512
#define EDn 512
#define Vn 10000
#define Ln 20
#define Tn 19

__device__ __forceinline__ float sigf(float x){ return 1.f/(1.f+__expf(-x)); }

// ---------------- setup kernels ----------------

// stable descending sort by caption_len (ties: original index ascending)
__global__ void k_order(const int* __restrict__ caption_len,
                        const int* __restrict__ captions,
                        int* __restrict__ order_i, int* __restrict__ declen_i,
                        int* __restrict__ caps_s,
                        float* __restrict__ out_caps, float* __restrict__ out_declen,
                        float* __restrict__ out_order)
{
  __shared__ int lens[Bn];
  int b = threadIdx.x;
  lens[b] = caption_len[b];
  __syncthreads();
  int lb = lens[b];
  int r = 0;
  for (int j = 0; j < Bn; ++j) {
    int lj = lens[j];
    r += (int)((lj > lb) || (lj == lb && j < b));
  }
  order_i[r] = b;
  declen_i[r] = lb - 1;
  out_order[r] = (float)b;
  out_declen[r] = (float)(lb - 1);
  for (int t = 0; t < Ln; ++t) {
    int cv = captions[b*Ln + t];
    caps_s[r*Ln + t] = cv;
    out_caps[r*Ln + t] = (float)cv;
  }
}

__global__ void k_rowmap(const int* __restrict__ order_i, int* __restrict__ rowmap)
{
  int m = blockIdx.x*256 + threadIdx.x;
  if (m < Bn*Pn) rowmap[m] = order_i[m/Pn]*Pn + (m % Pn);
}

__global__ void k_bsum(const float* __restrict__ bih, const float* __restrict__ bhh,
                       float* __restrict__ bsum)
{
  int j = blockIdx.x*256 + threadIdx.x;
  if (j < 4*Dn) bsum[j] = bih[j] + bhh[j];
}

__global__ void k_mean(const float* __restrict__ enc, const int* __restrict__ order_i,
                       float* __restrict__ mean_enc)
{
  int b = blockIdx.x;
  const float* eb = enc + (size_t)order_i[b]*Pn*ENCn;
  for (int e = threadIdx.x; e < ENCn; e += 256) {
    float s = 0.f;
    for (int p = 0; p < Pn; ++p) s += eb[(size_t)p*ENCn + e];
    mean_enc[b*ENCn + e] = s * (1.f/196.f);
  }
}

// ---------------- generic f32 GEMM: C[M,N] = A[M,K] @ B[N,K]^T (+bias) ----------------
// rowmap: optional gather of A rows. accum: C += result. rowmask/t: rows with
// t >= rowmask[m] write 0 (ragged pred masking).
#define TS 64
#define KT 16
__global__ __launch_bounds__(256) void k_gemm_tn(
    const float* __restrict__ A, const float* __restrict__ Bm,
    const float* __restrict__ bias, float* __restrict__ C,
    int M, int N, int K, int ldc,
    const int* __restrict__ rowmap, int accum,
    const int* __restrict__ rowmask, int t)
{
  __shared__ float As[KT][TS+1];
  __shared__ float Bs[KT][TS+1];
  int bm = blockIdx.y * TS, bn = blockIdx.x * TS;
  int tid = threadIdx.x;
  int tx = tid & 15, ty = tid >> 4;
  int lr = tid >> 2;          // 0..63: row within tile
  int lk = (tid & 3) * 4;     // 0,4,8,12: k offset
  float acc[4][4] = {};
  for (int k0 = 0; k0 < K; k0 += KT) {
    int m = bm + lr;
    if (m < M) {
      int mr = rowmap ? rowmap[m] : m;
      const float4 v = *(const float4*)(A + (size_t)mr*K + k0 + lk);
      As[lk+0][lr]=v.x; As[lk+1][lr]=v.y; As[lk+2][lr]=v.z; As[lk+3][lr]=v.w;
    } else {
      As[lk+0][lr]=0.f; As[lk+1][lr]=0.f; As[lk+2][lr]=0.f; As[lk+3][lr]=0.f;
    }
    int n = bn + lr;
    if (n < N) {
      const float4 v = *(const float4*)(Bm + (size_t)n*K + k0 + lk);
      Bs[lk+0][lr]=v.x; Bs[lk+1][lr]=v.y; Bs[lk+2][lr]=v.z; Bs[lk+3][lr]=v.w;
    } else {
      Bs[lk+0][lr]=0.f; Bs[lk+1][lr]=0.f; Bs[lk+2][lr]=0.f; Bs[lk+3][lr]=0.f;
    }
    __syncthreads();
    #pragma unroll
    for (int k = 0; k < KT; ++k) {
      float a0=As[k][ty*4+0], a1=As[k][ty*4+1], a2=As[k][ty*4+2], a3=As[k][ty*4+3];
      float b0=Bs[k][tx*4+0], b1=Bs[k][tx*4+1], b2=Bs[k][tx*4+2], b3=Bs[k][tx*4+3];
      acc[0][0]+=a0*b0; acc[0][1]+=a0*b1; acc[0][2]+=a0*b2; acc[0][3]+=a0*b3;
      acc[1][0]+=a1*b0; acc[1][1]+=a1*b1; acc[1][2]+=a1*b2; acc[1][3]+=a1*b3;
      acc[2][0]+=a2*b0; acc[2][1]+=a2*b1; acc[2][2]+=a2*b2; acc[2][3]+=a2*b3;
      acc[3][0]+=a3*b0; acc[3][1]+=a3*b1; acc[3][2]+=a3*b2; acc[3][3]+=a3*b3;
    }
    __syncthreads();
  }
  #pragma unroll
  for (int i = 0; i < 4; ++i) {
    int m = bm + ty*4 + i;
    if (m >= M) continue;
    bool zero = (rowmask != nullptr) && (t >= rowmask[m]);
    #pragma unroll
    for (int j = 0; j < 4; ++j) {
      int n = bn + tx*4 + j;
      if (n >= N) continue;
      float v = acc[i][j] + (bias ? bias[n] : 0.f);
      if (zero) v = 0.f;
      size_t idx = (size_t)m*ldc + n;
      if (accum) C[idx] += v; else C[idx] = v;
    }
  }
}

// ---------------- per-step kernels ----------------

// e[b,p] = sum_a relu(att1[b,p,a]+att2[b,a])*fa_w[a] + fa_b; softmax over p
__global__ __launch_bounds__(256) void k_e_softmax(
    const float* __restrict__ att1, const float* __restrict__ att2,
    const float* __restrict__ fa_w, const float* __restrict__ fa_b,
    float* __restrict__ alpha, float* __restrict__ out_alph,
    const int* __restrict__ declen_i, int t)
{
  int b = blockIdx.x;
  __shared__ float a2s[An];
  __shared__ float fws[An];
  __shared__ float es[Pn];
  __shared__ float wred[4];
  __shared__ float wsum[4];
  int tid = threadIdx.x;
  for (int i = tid; i < An; i += 256) { a2s[i] = att2[b*An + i]; fws[i] = fa_w[i]; }
  __syncthreads();
  int lane = tid & 63, w = tid >> 6;
  const float* a1b = att1 + (size_t)b*Pn*An;
  float fb = fa_b[0];
  for (int p = w; p < Pn; p += 4) {
    const float* row = a1b + (size_t)p*An;
    float s = 0.f;
    for (int a = lane; a < An; a += 64) {
      float v = row[a] + a2s[a];
      s += fmaxf(v, 0.f) * fws[a];
    }
    for (int off = 32; off; off >>= 1) s += __shfl_down(s, off);
    if (lane == 0) es[p] = s + fb;
  }
  __syncthreads();
  float m = -1e30f;
  for (int p = tid; p < Pn; p += 256) m = fmaxf(m, es[p]);
  for (int off = 32; off; off >>= 1) m = fmaxf(m, __shfl_down(m, off));
  if (lane == 0) wred[w] = m;
  __syncthreads();
  m = fmaxf(fmaxf(wred[0], wred[1]), fmaxf(wred[2], wred[3]));
  float s = 0.f;
  for (int p = tid; p < Pn; p += 256) { float ev = __expf(es[p] - m); es[p] = ev; s += ev; }
  for (int off = 32; off; off >>= 1) s += __shfl_down(s, off);
  if (lane == 0) wsum[w] = s;
  __syncthreads();
  s = wsum[0] + wsum[1] + wsum[2] + wsum[3];
  float inv = 1.f / s;
  bool active = (t < declen_i[b]);
  for (int p = tid; p < Pn; p += 256) {
    float al = es[p] * inv;
    alpha[b*Pn + p] = al;
    out_alph[(size_t)b*Tn*Pn + (size_t)t*Pn + p] = active ? al : 0.f;
  }
}

// awe[b,e] = sum_p alpha[b,p]*enc_sorted[b,p,e]; x[b,512+e] = sigmoid(gpre)*awe
__global__ __launch_bounds__(256) void k_awe_gate(
    const float* __restrict__ enc, const int* __restrict__ order_i,
    const float* __restrict__ alpha, const float* __restrict__ gpre,
    float* __restrict__ xbuf)
{
  int b = blockIdx.y;
  int e = blockIdx.x*256 + threadIdx.x;
  __shared__ float als[Pn];
  for (int p = threadIdx.x; p < Pn; p += 256) als[p] = alpha[b*Pn + p];
  __syncthreads();
  const float* eb = enc + (size_t)order_i[b]*Pn*ENCn;
  float s = 0.f;
  for (int p = 0; p < Pn; ++p) s += als[p] * eb[(size_t)p*ENCn + e];
  float g = sigf(gpre[b*ENCn + e]);
  xbuf[(size_t)b*2560 + 512 + e] = g * s;
}

__global__ void k_fill_x(const int* __restrict__ caps_s, const float* __restrict__ emb_w,
                         float* __restrict__ xbuf, int t)
{
  int b = blockIdx.x;
  int tok = caps_s[b*Ln + t];
  for (int i = threadIdx.x; i < EDn; i += 256)
    xbuf[(size_t)b*2560 + i] = emb_w[(size_t)tok*EDn + i];
}

__global__ void k_lstm(const float* __restrict__ gates, float* __restrict__ c,
                       float* __restrict__ h, const int* __restrict__ declen_i, int t)
{
  int b = blockIdx.x, d = threadIdx.x;
  float gi = gates[(size_t)b*2048 + d];
  float gf = gates[(size_t)b*2048 + 512 + d];
  float gg = gates[(size_t)b*2048 + 1024 + d];
  float go = gates[(size_t)b*2048 + 1536 + d];
  float cn = sigf(gf)*c[b*Dn + d] + sigf(gi)*tanhf(gg);
  float hn = sigf(go)*tanhf(cn);
  if (t < declen_i[b]) { h[b*Dn + d] = hn; c[b*Dn + d] = cn; }
}

// ---------------- launch ----------------

extern "C" void kernel_launch(void* const* d_in, const int* in_sizes, int n_in,
                              void* d_out, int out_size, void* d_ws, size_t ws_size,
                              hipStream_t stream)
{
  const float* enc     = (const float*)d_in[0];
  const int*   captions= (const int*)d_in[1];
  const int*   cap_len = (const int*)d_in[2];
  const float* emb_w   = (const float*)d_in[3];
  const float* Wih     = (const float*)d_in[4];
  const float* Whh     = (const float*)d_in[5];
  const float* bih     = (const float*)d_in[6];
  const float* bhh     = (const float*)d_in[7];
  const float* h0_w    = (const float*)d_in[8];
  const float* h0_b    = (const float*)d_in[9];
  const float* c0_w    = (const float*)d_in[10];
  const float* c0_b    = (const float*)d_in[11];
  const float* gate_w  = (const float*)d_in[12];
  const float* gate_b  = (const float*)d_in[13];
  const float* lin_w   = (const float*)d_in[14];
  const float* lin_b   = (const float*)d_in[15];
  const float* ea_w    = (const float*)d_in[16];
  const float* ea_b    = (const float*)d_in[17];
  const float* da_w    = (const float*)d_in[18];
  const float* da_b    = (const float*)d_in[19];
  const float* fa_w    = (const float*)d_in[20];
  const float* fa_b    = (const float*)d_in[21];

  float* out = (float*)d_out;
  float* out_pred   = out;                               // [128][19][10000]
  float* out_caps   = out + (size_t)Bn*Tn*Vn;            // [128][20]
  float* out_declen = out_caps + Bn*Ln;                  // [128]
  float* out_alph   = out_declen + Bn;                   // [128][19][196]
  float* out_order  = out_alph + (size_t)Bn*Tn*Pn;       // [128]

  char* wp = (char*)d_ws;
  auto alloc = [&](size_t bytes)->void* {
    void* p = (void*)wp; wp += (bytes + 255) & ~(size_t)255; return p;
  };
  int*   order_i  = (int*)alloc(Bn*4);
  int*   declen_i = (int*)alloc(Bn*4);
  int*   caps_s   = (int*)alloc(Bn*Ln*4);
  int*   rowmap   = (int*)alloc((size_t)Bn*Pn*4);
  float* mean_enc = (float*)alloc((size_t)Bn*ENCn*4);
  float* h        = (float*)alloc((size_t)Bn*Dn*4);
  float* c        = (float*)alloc((size_t)Bn*Dn*4);
  float* att1     = (float*)alloc((size_t)Bn*Pn*An*4);   // 51.4 MB
  float* att2     = (float*)alloc((size_t)Bn*An*4);
  float* alpha    = (float*)alloc((size_t)Bn*Pn*4);
  float* gpre     = (float*)alloc((size_t)Bn*ENCn*4);
  float* xbuf     = (float*)alloc((size_t)Bn*2560*4);
  float* gates    = (float*)alloc((size_t)Bn*2048*4);
  float* bsum     = (float*)alloc(2048*4);

  // setup
  k_order<<<1,128,0,stream>>>(cap_len, captions, order_i, declen_i, caps_s,
                              out_caps, out_declen, out_order);
  k_rowmap<<<(Bn*Pn+255)/256,256,0,stream>>>(order_i, rowmap);
  k_bsum<<<(2048+255)/256,256,0,stream>>>(bih, bhh, bsum);
  k_mean<<<Bn,256,0,stream>>>(enc, order_i, mean_enc);
  // h0 / c0
  k_gemm_tn<<<dim3(Dn/64, Bn/64),256,0,stream>>>(mean_enc, h0_w, h0_b, h,
      Bn, Dn, ENCn, Dn, nullptr, 0, nullptr, 0);
  k_gemm_tn<<<dim3(Dn/64, Bn/64),256,0,stream>>>(mean_enc, c0_w, c0_b, c,
      Bn, Dn, ENCn, Dn, nullptr, 0, nullptr, 0);
  // att1 = enc_sorted @ ea_w^T + ea_b  (row-gathered via rowmap)
  k_gemm_tn<<<dim3(An/64, (Bn*Pn)/64),256,0,stream>>>(enc, ea_w, ea_b, att1,
      Bn*Pn, An, ENCn, An, rowmap, 0, nullptr, 0);

  for (int t = 0; t < Tn; ++t) {
    // att2 = h @ da_w^T + da_b
    k_gemm_tn<<<dim3(An/64, Bn/64),256,0,stream>>>(h, da_w, da_b, att2,
        Bn, An, Dn, An, nullptr, 0, nullptr, 0);
    k_e_softmax<<<Bn,256,0,stream>>>(att1, att2, fa_w, fa_b, alpha, out_alph,
                                     declen_i, t);
    // gpre = h @ gate_w^T + gate_b
    k_gemm_tn<<<dim3(ENCn/64, Bn/64),256,0,stream>>>(h, gate_w, gate_b, gpre,
        Bn, ENCn, Dn, ENCn, nullptr, 0, nullptr, 0);
    k_awe_gate<<<dim3(ENCn/256, Bn),256,0,stream>>>(enc, order_i, alpha, gpre, xbuf);
    k_fill_x<<<Bn,256,0,stream>>>(caps_s, emb_w, xbuf, t);
    // gates = x @ Wih^T + (bih+bhh); gates += h @ Whh^T
    k_gemm_tn<<<dim3(2048/64, Bn/64),256,0,stream>>>(xbuf, Wih, bsum, gates,
        Bn, 2048, 2560, 2048, nullptr, 0, nullptr, 0);
    k_gemm_tn<<<dim3(2048/64, Bn/64),256,0,stream>>>(h, Whh, nullptr, gates,
        Bn, 2048, Dn, 2048, nullptr, 1, nullptr, 0);
    k_lstm<<<Bn,512,0,stream>>>(gates, c, h, declen_i, t);
    // pred[:, t, :] = active ? h_new @ lin_w^T + lin_b : 0
    k_gemm_tn<<<dim3((Vn+63)/64, Bn/64),256,0,stream>>>(h, lin_w, lin_b,
        out_pred + (size_t)t*Vn, Bn, Vn, Dn, Tn*Vn, nullptr, 0, declen_i, t);
  }
}

// Round 2
// 3084.513 us; speedup vs baseline: 3.6789x; 3.6789x over previous
//
#include <hip/hip_runtime.h>
#include <hip/hip_bf16.h>
#include <math.h>

#define Bn 128
#define Pn 196
#define ENCn 2048
#define Dn 512
#define An 512
#define EDn 512
#define Vn 10000
#define Ln 20
#define Tn 19

typedef short v8s __attribute__((ext_vector_type(8)));
typedef float v4f __attribute__((ext_vector_type(4)));

__device__ __forceinline__ float sigf(float x){ return 1.f/(1.f+__expf(-x)); }
__device__ __forceinline__ unsigned short f2bf(float f){
  unsigned u = __float_as_uint(f);
  return (unsigned short)((u + 0x7FFFu + ((u>>16)&1u)) >> 16);
}
__device__ __forceinline__ float bf2f(unsigned short h){
  return __uint_as_float(((unsigned)h)<<16);
}

// ---------------- setup kernels ----------------

__global__ void k_order(const int* __restrict__ caption_len,
                        const int* __restrict__ captions,
                        int* __restrict__ order_i, int* __restrict__ declen_i,
                        int* __restrict__ caps_s,
                        float* __restrict__ out_caps, float* __restrict__ out_declen,
                        float* __restrict__ out_order)
{
  __shared__ int lens[Bn];
  int b = threadIdx.x;
  lens[b] = caption_len[b];
  __syncthreads();
  int lb = lens[b];
  int r = 0;
  for (int j = 0; j < Bn; ++j) {
    int lj = lens[j];
    r += (int)((lj > lb) || (lj == lb && j < b));
  }
  order_i[r] = b;
  declen_i[r] = lb - 1;
  out_order[r] = (float)b;
  out_declen[r] = (float)(lb - 1);
  for (int t = 0; t < Ln; ++t) {
    int cv = captions[b*Ln + t];
    caps_s[r*Ln + t] = cv;
    out_caps[r*Ln + t] = (float)cv;
  }
}

__global__ void k_rowmap(const int* __restrict__ order_i, int* __restrict__ rowmap)
{
  int m = blockIdx.x*256 + threadIdx.x;
  if (m < Bn*Pn) rowmap[m] = order_i[m/Pn]*Pn + (m % Pn);
}

__global__ void k_setup_bias(const float* __restrict__ bih, const float* __restrict__ bhh,
                             const float* __restrict__ da_b, const float* __restrict__ gate_b,
                             const float* __restrict__ h0_b, const float* __restrict__ c0_b,
                             float* __restrict__ bsum, float* __restrict__ dg_b,
                             float* __restrict__ hc_b)
{
  int i = blockIdx.x*256 + threadIdx.x;
  if (i < 2048) bsum[i] = bih[i] + bhh[i];
  if (i < 2560) dg_b[i] = (i < 512) ? da_b[i] : gate_b[i-512];
  if (i < 1024) hc_b[i] = (i < 512) ? h0_b[i] : c0_b[i-512];
}

// f32 -> bf16 copy, n multiple of 4
__global__ void k_cvt(const float* __restrict__ src, unsigned short* __restrict__ dst, int n)
{
  int i = (blockIdx.x*256 + threadIdx.x)*4;
  if (i < n) {
    float4 v = *(const float4*)(src + i);
    dst[i+0]=f2bf(v.x); dst[i+1]=f2bf(v.y); dst[i+2]=f2bf(v.z); dst[i+3]=f2bf(v.w);
  }
}

// Wcat[2048][3072] = [Wih | Whh] in bf16
__global__ void k_wcat(const float* __restrict__ Wih, const float* __restrict__ Whh,
                       unsigned short* __restrict__ dst)
{
  int i = (blockIdx.x*256 + threadIdx.x)*4;
  if (i >= 2048*3072) return;
  int r = i/3072, j = i - r*3072;
  const float* s = (j < 2560) ? (Wih + (size_t)r*2560 + j) : (Whh + (size_t)r*512 + (j-2560));
  float4 v = *(const float4*)s;
  dst[i+0]=f2bf(v.x); dst[i+1]=f2bf(v.y); dst[i+2]=f2bf(v.z); dst[i+3]=f2bf(v.w);
}

// mean over P of sorted enc -> bf16 [B][ENC]
__global__ void k_mean(const float* __restrict__ enc, const int* __restrict__ order_i,
                       unsigned short* __restrict__ mean_bf)
{
  int b = blockIdx.x;
  const float* eb = enc + (size_t)order_i[b]*Pn*ENCn;
  for (int e = threadIdx.x; e < ENCn; e += 256) {
    float s = 0.f;
    for (int p = 0; p < Pn; ++p) s += eb[(size_t)p*ENCn + e];
    mean_bf[b*ENCn + e] = f2bf(s * (1.f/196.f));
  }
}

// split hc -> h, c (f32) + h_bf + xh h-part
__global__ void k_h2bf(const float* __restrict__ hc, float* __restrict__ h, float* __restrict__ c,
                       unsigned short* __restrict__ h_bf, unsigned short* __restrict__ xh)
{
  int b = blockIdx.x, d = threadIdx.x;
  float hv = hc[b*1024 + d];
  float cv = hc[b*1024 + 512 + d];
  h[b*Dn + d] = hv;
  c[b*Dn + d] = cv;
  unsigned short hb = f2bf(hv);
  h_bf[b*Dn + d] = hb;
  xh[(size_t)b*3072 + 2560 + d] = hb;
}

// ---------------- bf16 MFMA GEMM: C[M,N] = A[M,K] @ B[N,K]^T (+bias) ----------------
// 64x64 tile, BK=64, 4 waves (2x2), each wave 32x32 via 2x2 x (2 k-chunks) MFMAs.
// LDS XOR-swizzled: block (row,kb8) stored at short-offset row*64 + (kb8^(row&7))*8.
template<bool CVT_A, bool OUT_BF16>
__global__ __launch_bounds__(256) void k_mfma_gemm(
    const void* __restrict__ Ap, const unsigned short* __restrict__ Bw,
    const float* __restrict__ bias, void* __restrict__ Cp,
    int M, int N, int K, size_t ldc,
    const int* __restrict__ rowmapA,
    const int* __restrict__ rowmask, int t)
{
  __shared__ unsigned short smA[2][4096];
  __shared__ unsigned short smB[2][4096];
  const int tid = threadIdx.x;
  const int bm0 = blockIdx.y*64, bn0 = blockIdx.x*64;
  const int lane = tid & 63, w = tid >> 6;
  const int wr = w >> 1, wc = w & 1;
  const int lrow = lane & 15, kq = lane >> 4;

  v4f acc[2][2];
  #pragma unroll
  for (int i=0;i<2;++i)
    #pragma unroll
    for (int j=0;j<2;++j) acc[i][j] = (v4f)0.f;

  const float* Af = (const float*)Ap;
  const unsigned short* Ab = (const unsigned short*)Ap;
  const int nt = K >> 6;

  auto stage = [&](int buf, int k0) {
    #pragma unroll
    for (int it = 0; it < 2; ++it) {
      int s = it*256 + tid;          // slot 0..511 (16B each)
      int row = s >> 3;              // 0..63
      int kb  = (s & 7) ^ (row & 7); // source 8-elem k-block
      // A
      if constexpr (CVT_A) {
        int gr = bm0 + row;
        int grm = rowmapA ? rowmapA[gr] : gr;
        const float* src = Af + (size_t)grm*K + k0 + kb*8;
        float4 v0 = *(const float4*)src;
        float4 v1 = *(const float4*)(src+4);
        unsigned short* d = &smA[buf][s*8];
        d[0]=f2bf(v0.x); d[1]=f2bf(v0.y); d[2]=f2bf(v0.z); d[3]=f2bf(v0.w);
        d[4]=f2bf(v1.x); d[5]=f2bf(v1.y); d[6]=f2bf(v1.z); d[7]=f2bf(v1.w);
      } else {
        int gr = bm0 + row;
        const v8s v = *(const v8s*)(Ab + (size_t)gr*K + k0 + kb*8);
        *(v8s*)&smA[buf][s*8] = v;
      }
      // B (clamp ragged N)
      {
        int gn = bn0 + row; if (gn >= N) gn = N-1;
        const v8s v = *(const v8s*)(Bw + (size_t)gn*K + k0 + kb*8);
        *(v8s*)&smB[buf][s*8] = v;
      }
    }
  };

  auto compute = [&](int buf) {
    #pragma unroll
    for (int kc = 0; kc < 2; ++kc) {
      v8s aF[2], bF[2];
      #pragma unroll
      for (int mi = 0; mi < 2; ++mi) {
        int row = wr*32 + mi*16 + lrow;
        int kb = kc*4 + kq;
        aF[mi] = *(const v8s*)&smA[buf][row*64 + ((kb ^ (row&7))<<3)];
      }
      #pragma unroll
      for (int ni = 0; ni < 2; ++ni) {
        int row = wc*32 + ni*16 + lrow;
        int kb = kc*4 + kq;
        bF[ni] = *(const v8s*)&smB[buf][row*64 + ((kb ^ (row&7))<<3)];
      }
      #pragma unroll
      for (int mi = 0; mi < 2; ++mi)
        #pragma unroll
        for (int ni = 0; ni < 2; ++ni)
          acc[mi][ni] = __builtin_amdgcn_mfma_f32_16x16x32_bf16(aF[mi], bF[ni], acc[mi][ni], 0, 0, 0);
    }
  };

  stage(0, 0);
  __syncthreads();
  for (int tk = 0; tk < nt; ++tk) {
    if (tk + 1 < nt) stage((tk+1)&1, (tk+1)<<6);
    compute(tk&1);
    __syncthreads();
  }

  // epilogue: C/D layout col=lane&15, row=(lane>>4)*4+reg
  #pragma unroll
  for (int mi=0; mi<2; ++mi)
    #pragma unroll
    for (int ni=0; ni<2; ++ni) {
      #pragma unroll
      for (int r=0; r<4; ++r) {
        int m = bm0 + wr*32 + mi*16 + kq*4 + r;
        int n = bn0 + wc*32 + ni*16 + lrow;
        if (m < M && n < N) {
          float v = acc[mi][ni][r] + (bias ? bias[n] : 0.f);
          if (rowmask && t >= rowmask[m]) v = 0.f;
          if constexpr (OUT_BF16) ((unsigned short*)Cp)[(size_t)m*ldc + n] = f2bf(v);
          else ((float*)Cp)[(size_t)m*ldc + n] = v;
        }
      }
    }
}

// ---------------- per-step kernels ----------------

// e[b,p] = relu(att1_bf + att2) . fa_w + fa_b ; softmax over p
__global__ __launch_bounds__(256) void k_e_softmax(
    const unsigned short* __restrict__ att1, const float* __restrict__ att2g,
    const float* __restrict__ fa_w, const float* __restrict__ fa_b,
    float* __restrict__ alpha, float* __restrict__ out_alph,
    const int* __restrict__ declen_i, int t)
{
  int b = blockIdx.x;
  __shared__ float a2s[An];
  __shared__ float fws[An];
  __shared__ float es[Pn];
  __shared__ float wred[4];
  __shared__ float wsum[4];
  int tid = threadIdx.x;
  for (int i = tid; i < An; i += 256) { a2s[i] = att2g[(size_t)b*2560 + i]; fws[i] = fa_w[i]; }
  __syncthreads();
  int lane = tid & 63, w = tid >> 6;
  const unsigned short* a1b = att1 + (size_t)b*Pn*An;
  float fb = fa_b[0];
  for (int p = w; p < Pn; p += 4) {
    const v8s vv = *(const v8s*)(a1b + (size_t)p*An + lane*8);
    float s = 0.f;
    #pragma unroll
    for (int j = 0; j < 8; ++j) {
      int a = lane*8 + j;
      float v = bf2f((unsigned short)vv[j]) + a2s[a];
      s += fmaxf(v, 0.f) * fws[a];
    }
    for (int off = 32; off; off >>= 1) s += __shfl_down(s, off);
    if (lane == 0) es[p] = s + fb;
  }
  __syncthreads();
  float m = -1e30f;
  for (int p = tid; p < Pn; p += 256) m = fmaxf(m, es[p]);
  for (int off = 32; off; off >>= 1) m = fmaxf(m, __shfl_down(m, off));
  if (lane == 0) wred[w] = m;
  __syncthreads();
  m = fmaxf(fmaxf(wred[0], wred[1]), fmaxf(wred[2], wred[3]));
  float s = 0.f;
  for (int p = tid; p < Pn; p += 256) { float ev = __expf(es[p] - m); es[p] = ev; s += ev; }
  for (int off = 32; off; off >>= 1) s += __shfl_down(s, off);
  if (lane == 0) wsum[w] = s;
  __syncthreads();
  s = wsum[0] + wsum[1] + wsum[2] + wsum[3];
  float inv = 1.f / s;
  bool active = (t < declen_i[b]);
  for (int p = tid; p < Pn; p += 256) {
    float al = es[p] * inv;
    alpha[b*Pn + p] = al;
    out_alph[(size_t)b*Tn*Pn + (size_t)t*Pn + p] = active ? al : 0.f;
  }
}

// awe[b,e] = sum_p alpha*enc ; xh[b,512+e] = bf16(sigmoid(gpre)*awe)
// grid (ENC/128, B), 256 thr: tid -> (ec=tid&31 float4-col, ps=tid>>5 p-slice)
__global__ __launch_bounds__(256) void k_awe_gate(
    const float* __restrict__ enc, const int* __restrict__ order_i,
    const float* __restrict__ alpha, const float* __restrict__ att2g,
    unsigned short* __restrict__ xh)
{
  __shared__ float als[Pn];
  __shared__ float red[8][128];
  int b = blockIdx.y, tid = threadIdx.x;
  if (tid < Pn) als[tid] = alpha[b*Pn + tid];
  __syncthreads();
  int e0 = blockIdx.x*128;
  int ec = tid & 31, ps = tid >> 5;
  const float* eb = enc + (size_t)order_i[b]*Pn*ENCn + e0 + ec*4;
  float4 s = make_float4(0.f,0.f,0.f,0.f);
  for (int p = ps; p < Pn; p += 8) {
    float4 v = *(const float4*)(eb + (size_t)p*ENCn);
    float a = als[p];
    s.x += a*v.x; s.y += a*v.y; s.z += a*v.z; s.w += a*v.w;
  }
  red[ps][ec*4+0]=s.x; red[ps][ec*4+1]=s.y; red[ps][ec*4+2]=s.z; red[ps][ec*4+3]=s.w;
  __syncthreads();
  if (tid < 128) {
    float tsum = 0.f;
    #pragma unroll
    for (int k = 0; k < 8; ++k) tsum += red[k][tid];
    int e = e0 + tid;
    float g = sigf(att2g[(size_t)b*2560 + 512 + e]);
    xh[(size_t)b*3072 + 512 + e] = f2bf(g*tsum);
  }
}

__global__ void k_fill_x(const int* __restrict__ caps_s, const float* __restrict__ emb_w,
                         unsigned short* __restrict__ xh, int t)
{
  int b = blockIdx.x;
  int tok = caps_s[b*Ln + t];
  for (int i = threadIdx.x; i < EDn; i += 256)
    xh[(size_t)b*3072 + i] = f2bf(emb_w[(size_t)tok*EDn + i]);
}

__global__ void k_lstm(const float* __restrict__ gates, float* __restrict__ c,
                       float* __restrict__ h, unsigned short* __restrict__ h_bf,
                       unsigned short* __restrict__ xh,
                       const int* __restrict__ declen_i, int t)
{
  int b = blockIdx.x, d = threadIdx.x;
  float gi = gates[(size_t)b*2048 + d];
  float gf = gates[(size_t)b*2048 + 512 + d];
  float gg = gates[(size_t)b*2048 + 1024 + d];
  float go = gates[(size_t)b*2048 + 1536 + d];
  float cn = sigf(gf)*c[b*Dn + d] + sigf(gi)*tanhf(gg);
  float hn = sigf(go)*tanhf(cn);
  if (t < declen_i[b]) {
    h[b*Dn + d] = hn; c[b*Dn + d] = cn;
    unsigned short hb = f2bf(hn);
    h_bf[b*Dn + d] = hb;
    xh[(size_t)b*3072 + 2560 + d] = hb;
  }
}

// ---------------- launch ----------------

extern "C" void kernel_launch(void* const* d_in, const int* in_sizes, int n_in,
                              void* d_out, int out_size, void* d_ws, size_t ws_size,
                              hipStream_t stream)
{
  const float* enc     = (const float*)d_in[0];
  const int*   captions= (const int*)d_in[1];
  const int*   cap_len = (const int*)d_in[2];
  const float* emb_w   = (const float*)d_in[3];
  const float* Wih     = (const float*)d_in[4];
  const float* Whh     = (const float*)d_in[5];
  const float* bih     = (const float*)d_in[6];
  const float* bhh     = (const float*)d_in[7];
  const float* h0_w    = (const float*)d_in[8];
  const float* h0_b    = (const float*)d_in[9];
  const float* c0_w    = (const float*)d_in[10];
  const float* c0_b    = (const float*)d_in[11];
  const float* gate_w  = (const float*)d_in[12];
  const float* gate_b  = (const float*)d_in[13];
  const float* lin_w   = (const float*)d_in[14];
  const float* lin_b   = (const float*)d_in[15];
  const float* ea_w    = (const float*)d_in[16];
  const float* ea_b    = (const float*)d_in[17];
  const float* da_w    = (const float*)d_in[18];
  const float* da_b    = (const float*)d_in[19];
  const float* fa_w    = (const float*)d_in[20];
  const float* fa_b    = (const float*)d_in[21];

  float* out = (float*)d_out;
  float* out_pred   = out;                               // [128][19][10000]
  float* out_caps   = out + (size_t)Bn*Tn*Vn;            // [128][20]
  float* out_declen = out_caps + Bn*Ln;                  // [128]
  float* out_alph   = out_declen + Bn;                   // [128][19][196]
  float* out_order  = out_alph + (size_t)Bn*Tn*Pn;       // [128]

  char* wp = (char*)d_ws;
  auto alloc = [&](size_t bytes)->void* {
    void* p = (void*)wp; wp += (bytes + 255) & ~(size_t)255; return p;
  };
  int*   order_i  = (int*)alloc(Bn*4);
  int*   declen_i = (int*)alloc(Bn*4);
  int*   caps_s   = (int*)alloc(Bn*Ln*4);
  int*   rowmap   = (int*)alloc((size_t)Bn*Pn*4);
  unsigned short* mean_bf = (unsigned short*)alloc((size_t)Bn*ENCn*2);
  float* hc       = (float*)alloc((size_t)Bn*1024*4);
  float* h        = (float*)alloc((size_t)Bn*Dn*4);
  float* c        = (float*)alloc((size_t)Bn*Dn*4);
  unsigned short* h_bf = (unsigned short*)alloc((size_t)Bn*Dn*2);
  unsigned short* xh   = (unsigned short*)alloc((size_t)Bn*3072*2);
  unsigned short* att1 = (unsigned short*)alloc((size_t)Bn*Pn*An*2);   // 25.7 MB
  float* att2g    = (float*)alloc((size_t)Bn*2560*4);
  float* alpha    = (float*)alloc((size_t)Bn*Pn*4);
  float* gates    = (float*)alloc((size_t)Bn*2048*4);
  unsigned short* ea_bf   = (unsigned short*)alloc((size_t)An*ENCn*2);
  unsigned short* lin_bf  = (unsigned short*)alloc((size_t)Vn*Dn*2);
  unsigned short* h0c0_bf = (unsigned short*)alloc((size_t)1024*ENCn*2);
  unsigned short* dg_bf   = (unsigned short*)alloc((size_t)2560*Dn*2);
  unsigned short* wcat_bf = (unsigned short*)alloc((size_t)2048*3072*2);
  float* bsum = (float*)alloc(2048*4);
  float* dg_b = (float*)alloc(2560*4);
  float* hc_b = (float*)alloc(1024*4);

  // ---- setup ----
  k_order<<<1,128,0,stream>>>(cap_len, captions, order_i, declen_i, caps_s,
                              out_caps, out_declen, out_order);
  k_rowmap<<<(Bn*Pn+255)/256,256,0,stream>>>(order_i, rowmap);
  k_setup_bias<<<10,256,0,stream>>>(bih, bhh, da_b, gate_b, h0_b, c0_b, bsum, dg_b, hc_b);
  k_cvt<<<(An*ENCn/4+255)/256,256,0,stream>>>(ea_w, ea_bf, An*ENCn);
  k_cvt<<<(Vn*Dn/4+255)/256,256,0,stream>>>(lin_w, lin_bf, Vn*Dn);
  k_cvt<<<(Dn*ENCn/4+255)/256,256,0,stream>>>(h0_w, h0c0_bf, Dn*ENCn);
  k_cvt<<<(Dn*ENCn/4+255)/256,256,0,stream>>>(c0_w, h0c0_bf + (size_t)512*ENCn, Dn*ENCn);
  k_cvt<<<(An*Dn/4+255)/256,256,0,stream>>>(da_w, dg_bf, An*Dn);
  k_cvt<<<(ENCn*Dn/4+255)/256,256,0,stream>>>(gate_w, dg_bf + (size_t)512*Dn, ENCn*Dn);
  k_wcat<<<(2048*3072/4+255)/256,256,0,stream>>>(Wih, Whh, wcat_bf);
  k_mean<<<Bn,256,0,stream>>>(enc, order_i, mean_bf);

  // h0/c0: [128,1024] = mean_bf @ h0c0_w^T
  k_mfma_gemm<false,false><<<dim3(16,2),256,0,stream>>>(
      mean_bf, h0c0_bf, hc_b, hc, Bn, 1024, ENCn, 1024, nullptr, nullptr, 0);
  k_h2bf<<<Bn,512,0,stream>>>(hc, h, c, h_bf, xh);

  // att1 (bf16 out) = enc_sorted(f32, gathered, cvt in-kernel) @ ea_w^T
  k_mfma_gemm<true,true><<<dim3(8,392),256,0,stream>>>(
      enc, ea_bf, ea_b, att1, Bn*Pn, An, ENCn, An, rowmap, nullptr, 0);

  for (int t = 0; t < Tn; ++t) {
    // att2|gpre = h @ [da_w;gate_w]^T : [128,2560]
    k_mfma_gemm<false,false><<<dim3(40,2),256,0,stream>>>(
        h_bf, dg_bf, dg_b, att2g, Bn, 2560, Dn, 2560, nullptr, nullptr, 0);
    k_e_softmax<<<Bn,256,0,stream>>>(att1, att2g, fa_w, fa_b, alpha, out_alph, declen_i, t);
    k_awe_gate<<<dim3(ENCn/128,Bn),256,0,stream>>>(enc, order_i, alpha, att2g, xh);
    k_fill_x<<<Bn,256,0,stream>>>(caps_s, emb_w, xh, t);
    // gates = [emb|awe|h] @ [Wih|Whh]^T : [128,2048]
    k_mfma_gemm<false,false><<<dim3(32,2),256,0,stream>>>(
        xh, wcat_bf, bsum, gates, Bn, 2048, 3072, 2048, nullptr, nullptr, 0);
    k_lstm<<<Bn,512,0,stream>>>(gates, c, h, h_bf, xh, declen_i, t);
    // pred[:,t,:] = active ? h @ lin_w^T + lin_b : 0
    k_mfma_gemm<false,false><<<dim3((Vn+63)/64,2),256,0,stream>>>(
        h_bf, lin_bf, lin_b, out_pred + (size_t)t*Vn, Bn, Vn, Dn, (size_t)Tn*Vn,
        nullptr, declen_i, t);
  }
}

// Round 3
// 2240.806 us; speedup vs baseline: 5.0640x; 1.3765x over previous
//
#include <hip/hip_runtime.h>
#include <hip/hip_bf16.h>
#include <math.h>

#define Bn 128
#define Pn 196
#define ENCn 2048
#define Dn 512
#define An 512
#define EDn 512
#define Vn 10000
#define Ln 20
#define Tn 19

typedef short v8s __attribute__((ext_vector_type(8)));
typedef float v4f __attribute__((ext_vector_type(4)));

__device__ __forceinline__ float sigf(float x){ return 1.f/(1.f+__expf(-x)); }
__device__ __forceinline__ unsigned short f2bf(float f){
  unsigned u = __float_as_uint(f);
  return (unsigned short)((u + 0x7FFFu + ((u>>16)&1u)) >> 16);
}
__device__ __forceinline__ float bf2f(unsigned short h){
  return __uint_as_float(((unsigned)h)<<16);
}

// ---------------- setup kernels ----------------

__global__ void k_order(const int* __restrict__ caption_len,
                        const int* __restrict__ captions,
                        int* __restrict__ order_i, int* __restrict__ declen_i,
                        int* __restrict__ caps_s,
                        float* __restrict__ out_caps, float* __restrict__ out_declen,
                        float* __restrict__ out_order)
{
  __shared__ int lens[Bn];
  int b = threadIdx.x;
  lens[b] = caption_len[b];
  __syncthreads();
  int lb = lens[b];
  int r = 0;
  for (int j = 0; j < Bn; ++j) {
    int lj = lens[j];
    r += (int)((lj > lb) || (lj == lb && j < b));
  }
  order_i[r] = b;
  declen_i[r] = lb - 1;
  out_order[r] = (float)b;
  out_declen[r] = (float)(lb - 1);
  for (int t = 0; t < Ln; ++t) {
    int cv = captions[b*Ln + t];
    caps_s[r*Ln + t] = cv;
    out_caps[r*Ln + t] = (float)cv;
  }
}

__global__ void k_setup_bias(const float* __restrict__ bih, const float* __restrict__ bhh,
                             const float* __restrict__ da_b, const float* __restrict__ gate_b,
                             const float* __restrict__ h0_b, const float* __restrict__ c0_b,
                             float* __restrict__ bsum, float* __restrict__ dg_b,
                             float* __restrict__ hc_b)
{
  int i = blockIdx.x*256 + threadIdx.x;
  if (i < 2048) bsum[i] = bih[i] + bhh[i];
  if (i < 2560) dg_b[i] = (i < 512) ? da_b[i] : gate_b[i-512];
  if (i < 1024) hc_b[i] = (i < 512) ? h0_b[i] : c0_b[i-512];
}

__global__ void k_cvt(const float* __restrict__ src, unsigned short* __restrict__ dst, int n)
{
  int i = (blockIdx.x*256 + threadIdx.x)*4;
  if (i < n) {
    float4 v = *(const float4*)(src + i);
    dst[i+0]=f2bf(v.x); dst[i+1]=f2bf(v.y); dst[i+2]=f2bf(v.z); dst[i+3]=f2bf(v.w);
  }
}

__global__ void k_wcat(const float* __restrict__ Wih, const float* __restrict__ Whh,
                       unsigned short* __restrict__ dst)
{
  int i = (blockIdx.x*256 + threadIdx.x)*4;
  if (i >= 2048*3072) return;
  int r = i/3072, j = i - r*3072;
  const float* s = (j < 2560) ? (Wih + (size_t)r*2560 + j) : (Whh + (size_t)r*512 + (j-2560));
  float4 v = *(const float4*)s;
  dst[i+0]=f2bf(v.x); dst[i+1]=f2bf(v.y); dst[i+2]=f2bf(v.z); dst[i+3]=f2bf(v.w);
}

// sorted gather + f32->bf16: enc_bf[b_sorted][p][e]
__global__ void k_cvt_enc(const float* __restrict__ enc, const int* __restrict__ order_i,
                          unsigned short* __restrict__ dst)
{
  int id = blockIdx.x;               // b*196+p
  int b = id / Pn, p = id - b*Pn;
  const float* src = enc + ((size_t)order_i[b]*Pn + p)*ENCn;
  unsigned short* d = dst + (size_t)id*ENCn;
  int i = threadIdx.x*8;
  float4 v0 = *(const float4*)(src+i), v1 = *(const float4*)(src+i+4);
  d[i+0]=f2bf(v0.x); d[i+1]=f2bf(v0.y); d[i+2]=f2bf(v0.z); d[i+3]=f2bf(v0.w);
  d[i+4]=f2bf(v1.x); d[i+5]=f2bf(v1.y); d[i+6]=f2bf(v1.z); d[i+7]=f2bf(v1.w);
}

// mean over P of sorted bf16 enc -> bf16 [B][ENC]
__global__ void k_mean(const unsigned short* __restrict__ enc_bf,
                       unsigned short* __restrict__ mean_bf)
{
  int b = blockIdx.x;
  const unsigned short* eb = enc_bf + (size_t)b*Pn*ENCn;
  for (int e = threadIdx.x; e < ENCn; e += 256) {
    float s = 0.f;
    for (int p = 0; p < Pn; ++p) s += bf2f(eb[(size_t)p*ENCn + e]);
    mean_bf[b*ENCn + e] = f2bf(s * (1.f/196.f));
  }
}

__global__ void k_zero(uint4* __restrict__ p, int n)
{
  int i = blockIdx.x*256 + threadIdx.x;
  if (i < n) p[i] = uint4{0,0,0,0};
}

// all 19 embedding slices -> xh_all[t][b][0:512]
__global__ void k_emb_all(const int* __restrict__ caps_s, const float* __restrict__ emb_w,
                          unsigned short* __restrict__ xh_all)
{
  int id = blockIdx.x; int t = id >> 7, b = id & 127;
  int tok = caps_s[b*Ln + t];
  const float* src = emb_w + (size_t)tok*EDn;
  unsigned short* d = xh_all + ((size_t)t*Bn + b)*3072;
  int i = threadIdx.x*2;
  float2 v = *(const float2*)(src+i);
  d[i] = f2bf(v.x); d[i+1] = f2bf(v.y);
}

__global__ void k_h2bf(const float* __restrict__ hc, float* __restrict__ h, float* __restrict__ c,
                       unsigned short* __restrict__ h_bf, unsigned short* __restrict__ xh_all)
{
  int b = blockIdx.x, d = threadIdx.x;
  float hv = hc[b*1024 + d];
  float cv = hc[b*1024 + 512 + d];
  h[b*Dn + d] = hv;
  c[b*Dn + d] = cv;
  unsigned short hb = f2bf(hv);
  h_bf[b*Dn + d] = hb;
  xh_all[(size_t)b*3072 + 2560 + d] = hb;
}

// ---------------- bf16 MFMA GEMM: C[M,N] = A[M,K] @ B[N,K]^T (+bias) ----------------
// MODE 0: grid (N/64, M/64). MODE 1: att1 XCD-swizzle, grid (3136) linear,
//   panels=392 rows, cols=8; each XCD owns 49 panels, iterated in 8-panel x 8-col
//   groups so a panel's 8 col-blocks are same-XCD and L2-resident.
// actlen/t: sorted declen early-exit (rows with actlen<=t inactive; prefix-active).
// zero_skip: skipped tiles write 0 (pred). rowmask: per-row zeroing in epilogue.
template<int MODE, bool OUT_BF16>
__global__ __launch_bounds__(256) void k_mfma_gemm(
    const unsigned short* __restrict__ Aw, const unsigned short* __restrict__ Bw,
    const float* __restrict__ bias, void* __restrict__ Cp,
    int M, int N, int K, size_t ldc,
    const int* __restrict__ actlen, int t, int zero_skip,
    const int* __restrict__ rowmask)
{
  __shared__ unsigned short smA[2][4096];
  __shared__ unsigned short smB[2][4096];
  const int tid = threadIdx.x;
  int bm0, bn0;
  if constexpr (MODE == 1) {
    int id = blockIdx.x;
    int xcd = id & 7, j = id >> 3;
    int g = j >> 6, rem = j & 63;
    int panel, col;
    if (g < 6) { panel = xcd*49 + g*8 + (rem & 7); col = rem >> 3; }
    else       { panel = xcd*49 + 48;              col = rem; }
    bm0 = panel*64; bn0 = col*64;
  } else {
    bm0 = blockIdx.y*64; bn0 = blockIdx.x*64;
  }

  if (MODE == 0 && actlen && actlen[bm0] <= t) {
    if (zero_skip) {
      float* C = (float*)Cp;
      int mrow = tid >> 4, ncol = (tid & 15) * 4;
      int n = bn0 + ncol;
      if (n < N) {
        #pragma unroll
        for (int i = 0; i < 4; ++i) {
          int m = bm0 + mrow + i*16;
          if (m < M) *(float4*)(C + (size_t)m*ldc + n) = make_float4(0.f,0.f,0.f,0.f);
        }
      }
    }
    return;
  }

  const int lane = tid & 63, w = tid >> 6;
  const int wr = w >> 1, wc = w & 1;
  const int lrow = lane & 15, kq = lane >> 4;

  v4f acc[2][2];
  #pragma unroll
  for (int i=0;i<2;++i)
    #pragma unroll
    for (int j=0;j<2;++j) acc[i][j] = (v4f)0.f;

  const int nt = K >> 6;

  auto stage = [&](int buf, int k0) {
    #pragma unroll
    for (int it = 0; it < 2; ++it) {
      int s = it*256 + tid;          // slot 0..511 (16B each)
      int row = s >> 3;              // 0..63
      int kb  = (s & 7) ^ (row & 7); // source 8-elem k-block (swizzled)
      {
        int gr = bm0 + row;
        const v8s v = *(const v8s*)(Aw + (size_t)gr*K + k0 + kb*8);
        *(v8s*)&smA[buf][s*8] = v;
      }
      {
        int gn = bn0 + row; if (gn >= N) gn = N-1;
        const v8s v = *(const v8s*)(Bw + (size_t)gn*K + k0 + kb*8);
        *(v8s*)&smB[buf][s*8] = v;
      }
    }
  };

  auto compute = [&](int buf) {
    #pragma unroll
    for (int kc = 0; kc < 2; ++kc) {
      v8s aF[2], bF[2];
      #pragma unroll
      for (int mi = 0; mi < 2; ++mi) {
        int row = wr*32 + mi*16 + lrow;
        int kb = kc*4 + kq;
        aF[mi] = *(const v8s*)&smA[buf][row*64 + ((kb ^ (row&7))<<3)];
      }
      #pragma unroll
      for (int ni = 0; ni < 2; ++ni) {
        int row = wc*32 + ni*16 + lrow;
        int kb = kc*4 + kq;
        bF[ni] = *(const v8s*)&smB[buf][row*64 + ((kb ^ (row&7))<<3)];
      }
      #pragma unroll
      for (int mi = 0; mi < 2; ++mi)
        #pragma unroll
        for (int ni = 0; ni < 2; ++ni)
          acc[mi][ni] = __builtin_amdgcn_mfma_f32_16x16x32_bf16(aF[mi], bF[ni], acc[mi][ni], 0, 0, 0);
    }
  };

  stage(0, 0);
  __syncthreads();
  for (int tk = 0; tk < nt; ++tk) {
    if (tk + 1 < nt) stage((tk+1)&1, (tk+1)<<6);
    compute(tk&1);
    __syncthreads();
  }

  #pragma unroll
  for (int mi=0; mi<2; ++mi)
    #pragma unroll
    for (int ni=0; ni<2; ++ni) {
      #pragma unroll
      for (int r=0; r<4; ++r) {
        int m = bm0 + wr*32 + mi*16 + kq*4 + r;
        int n = bn0 + wc*32 + ni*16 + lrow;
        if (m < M && n < N) {
          float v = acc[mi][ni][r] + (bias ? bias[n] : 0.f);
          if (rowmask && t >= rowmask[m]) v = 0.f;
          if constexpr (OUT_BF16) ((unsigned short*)Cp)[(size_t)m*ldc + n] = f2bf(v);
          else ((float*)Cp)[(size_t)m*ldc + n] = v;
        }
      }
    }
}

// ---------------- per-step kernels ----------------

__global__ __launch_bounds__(256) void k_e_softmax(
    const unsigned short* __restrict__ att1, const float* __restrict__ att2g,
    const float* __restrict__ fa_w, const float* __restrict__ fa_b,
    float* __restrict__ alpha, float* __restrict__ out_alph,
    const int* __restrict__ declen_i, int t)
{
  int b = blockIdx.x;
  int tid = threadIdx.x;
  if (t >= declen_i[b]) {
    for (int p = tid; p < Pn; p += 256)
      out_alph[(size_t)b*Tn*Pn + (size_t)t*Pn + p] = 0.f;
    return;
  }
  __shared__ float a2s[An];
  __shared__ float fws[An];
  __shared__ float es[Pn];
  __shared__ float wred[4];
  __shared__ float wsum[4];
  for (int i = tid; i < An; i += 256) { a2s[i] = att2g[(size_t)b*2560 + i]; fws[i] = fa_w[i]; }
  __syncthreads();
  int lane = tid & 63, w = tid >> 6;
  const unsigned short* a1b = att1 + (size_t)b*Pn*An;
  float fb = fa_b[0];
  for (int p = w; p < Pn; p += 4) {
    const v8s vv = *(const v8s*)(a1b + (size_t)p*An + lane*8);
    float s = 0.f;
    #pragma unroll
    for (int j = 0; j < 8; ++j) {
      int a = lane*8 + j;
      float v = bf2f((unsigned short)vv[j]) + a2s[a];
      s += fmaxf(v, 0.f) * fws[a];
    }
    for (int off = 32; off; off >>= 1) s += __shfl_down(s, off);
    if (lane == 0) es[p] = s + fb;
  }
  __syncthreads();
  float m = -1e30f;
  for (int p = tid; p < Pn; p += 256) m = fmaxf(m, es[p]);
  for (int off = 32; off; off >>= 1) m = fmaxf(m, __shfl_down(m, off));
  if (lane == 0) wred[w] = m;
  __syncthreads();
  m = fmaxf(fmaxf(wred[0], wred[1]), fmaxf(wred[2], wred[3]));
  float s = 0.f;
  for (int p = tid; p < Pn; p += 256) { float ev = __expf(es[p] - m); es[p] = ev; s += ev; }
  for (int off = 32; off; off >>= 1) s += __shfl_down(s, off);
  if (lane == 0) wsum[w] = s;
  __syncthreads();
  s = wsum[0] + wsum[1] + wsum[2] + wsum[3];
  float inv = 1.f / s;
  for (int p = tid; p < Pn; p += 256) {
    float al = es[p] * inv;
    alpha[b*Pn + p] = al;
    out_alph[(size_t)b*Tn*Pn + (size_t)t*Pn + p] = al;
  }
}

// awe[b,e] = sum_p alpha*enc_bf ; xh_t[b,512+e] = bf16(sigmoid(gpre)*awe)
// grid (ENC/256, B): tid -> (ec=tid&31 8-elem chunk, ps=tid>>5 p-slice)
__global__ __launch_bounds__(256) void k_awe_gate(
    const unsigned short* __restrict__ enc_bf,
    const float* __restrict__ alpha, const float* __restrict__ att2g,
    unsigned short* __restrict__ xh_t, const int* __restrict__ declen_i, int t)
{
  int b = blockIdx.y;
  if (t >= declen_i[b]) return;
  __shared__ float als[Pn];
  __shared__ float red[8][256];
  int tid = threadIdx.x;
  if (tid < Pn) als[tid] = alpha[b*Pn + tid];
  __syncthreads();
  int e0 = blockIdx.x*256;
  int ec = tid & 31, ps = tid >> 5;
  const unsigned short* eb = enc_bf + (size_t)b*Pn*ENCn + e0 + ec*8;
  float s[8] = {};
  for (int p = ps; p < Pn; p += 8) {
    v8s v = *(const v8s*)(eb + (size_t)p*ENCn);
    float a = als[p];
    #pragma unroll
    for (int j = 0; j < 8; ++j) s[j] += a * bf2f((unsigned short)v[j]);
  }
  #pragma unroll
  for (int j = 0; j < 8; ++j) red[ps][ec*8+j] = s[j];
  __syncthreads();
  {
    int e = tid;
    float tsum = 0.f;
    #pragma unroll
    for (int k = 0; k < 8; ++k) tsum += red[k][e];
    int eg = e0 + e;
    float g = sigf(att2g[(size_t)b*2560 + 512 + eg]);
    xh_t[(size_t)b*3072 + 512 + eg] = f2bf(g*tsum);
  }
}

__global__ void k_lstm(const float* __restrict__ gates, float* __restrict__ c,
                       float* __restrict__ h, unsigned short* __restrict__ h_bf,
                       unsigned short* __restrict__ xh_all,
                       const int* __restrict__ declen_i, int t)
{
  int b = blockIdx.x, d = threadIdx.x;
  if (t >= declen_i[b]) return;
  float gi = gates[(size_t)b*2048 + d];
  float gf = gates[(size_t)b*2048 + 512 + d];
  float gg = gates[(size_t)b*2048 + 1024 + d];
  float go = gates[(size_t)b*2048 + 1536 + d];
  float cn = sigf(gf)*c[b*Dn + d] + sigf(gi)*tanhf(gg);
  float hn = sigf(go)*tanhf(cn);
  h[b*Dn + d] = hn; c[b*Dn + d] = cn;
  unsigned short hb = f2bf(hn);
  h_bf[b*Dn + d] = hb;
  if (t + 1 < Tn)
    xh_all[((size_t)(t+1)*Bn + b)*3072 + 2560 + d] = hb;
}

// ---------------- launch ----------------

extern "C" void kernel_launch(void* const* d_in, const int* in_sizes, int n_in,
                              void* d_out, int out_size, void* d_ws, size_t ws_size,
                              hipStream_t stream)
{
  const float* enc     = (const float*)d_in[0];
  const int*   captions= (const int*)d_in[1];
  const int*   cap_len = (const int*)d_in[2];
  const float* emb_w   = (const float*)d_in[3];
  const float* Wih     = (const float*)d_in[4];
  const float* Whh     = (const float*)d_in[5];
  const float* bih     = (const float*)d_in[6];
  const float* bhh     = (const float*)d_in[7];
  const float* h0_w    = (const float*)d_in[8];
  const float* h0_b    = (const float*)d_in[9];
  const float* c0_w    = (const float*)d_in[10];
  const float* c0_b    = (const float*)d_in[11];
  const float* gate_w  = (const float*)d_in[12];
  const float* gate_b  = (const float*)d_in[13];
  const float* lin_w   = (const float*)d_in[14];
  const float* lin_b   = (const float*)d_in[15];
  const float* ea_w    = (const float*)d_in[16];
  const float* ea_b    = (const float*)d_in[17];
  const float* da_w    = (const float*)d_in[18];
  const float* da_b    = (const float*)d_in[19];
  const float* fa_w    = (const float*)d_in[20];
  const float* fa_b    = (const float*)d_in[21];

  float* out = (float*)d_out;
  float* out_pred   = out;                               // [128][19][10000]
  float* out_caps   = out + (size_t)Bn*Tn*Vn;            // [128][20]
  float* out_declen = out_caps + Bn*Ln;                  // [128]
  float* out_alph   = out_declen + Bn;                   // [128][19][196]
  float* out_order  = out_alph + (size_t)Bn*Tn*Pn;       // [128]

  char* wp = (char*)d_ws;
  auto alloc = [&](size_t bytes)->void* {
    void* p = (void*)wp; wp += (bytes + 255) & ~(size_t)255; return p;
  };
  int*   order_i  = (int*)alloc(Bn*4);
  int*   declen_i = (int*)alloc(Bn*4);
  int*   caps_s   = (int*)alloc(Bn*Ln*4);
  unsigned short* enc_bf  = (unsigned short*)alloc((size_t)Bn*Pn*ENCn*2);  // 102.8 MB
  unsigned short* mean_bf = (unsigned short*)alloc((size_t)Bn*ENCn*2);
  float* hc       = (float*)alloc((size_t)Bn*1024*4);
  float* h        = (float*)alloc((size_t)Bn*Dn*4);
  float* c        = (float*)alloc((size_t)Bn*Dn*4);
  unsigned short* h_bf   = (unsigned short*)alloc((size_t)Bn*Dn*2);
  unsigned short* xh_all = (unsigned short*)alloc((size_t)Tn*Bn*3072*2);   // 14.9 MB
  unsigned short* att1   = (unsigned short*)alloc((size_t)Bn*Pn*An*2);     // 25.7 MB
  float* att2g    = (float*)alloc((size_t)Bn*2560*4);
  float* alpha    = (float*)alloc((size_t)Bn*Pn*4);
  float* gates    = (float*)alloc((size_t)Bn*2048*4);
  unsigned short* ea_bf   = (unsigned short*)alloc((size_t)An*ENCn*2);
  unsigned short* lin_bf  = (unsigned short*)alloc((size_t)Vn*Dn*2);
  unsigned short* h0c0_bf = (unsigned short*)alloc((size_t)1024*ENCn*2);
  unsigned short* dg_bf   = (unsigned short*)alloc((size_t)2560*Dn*2);
  unsigned short* wcat_bf = (unsigned short*)alloc((size_t)2048*3072*2);
  float* bsum = (float*)alloc(2048*4);
  float* dg_b = (float*)alloc(2560*4);
  float* hc_b = (float*)alloc(1024*4);

  // ---- setup ----
  k_order<<<1,128,0,stream>>>(cap_len, captions, order_i, declen_i, caps_s,
                              out_caps, out_declen, out_order);
  k_setup_bias<<<10,256,0,stream>>>(bih, bhh, da_b, gate_b, h0_b, c0_b, bsum, dg_b, hc_b);
  k_cvt<<<(An*ENCn/4+255)/256,256,0,stream>>>(ea_w, ea_bf, An*ENCn);
  k_cvt<<<(Vn*Dn/4+255)/256,256,0,stream>>>(lin_w, lin_bf, Vn*Dn);
  k_cvt<<<(Dn*ENCn/4+255)/256,256,0,stream>>>(h0_w, h0c0_bf, Dn*ENCn);
  k_cvt<<<(Dn*ENCn/4+255)/256,256,0,stream>>>(c0_w, h0c0_bf + (size_t)512*ENCn, Dn*ENCn);
  k_cvt<<<(An*Dn/4+255)/256,256,0,stream>>>(da_w, dg_bf, An*Dn);
  k_cvt<<<(ENCn*Dn/4+255)/256,256,0,stream>>>(gate_w, dg_bf + (size_t)512*Dn, ENCn*Dn);
  k_wcat<<<(2048*3072/4+255)/256,256,0,stream>>>(Wih, Whh, wcat_bf);
  k_cvt_enc<<<Bn*Pn,256,0,stream>>>(enc, order_i, enc_bf);
  k_mean<<<Bn,256,0,stream>>>(enc_bf, mean_bf);
  k_zero<<<((int)((size_t)Tn*Bn*3072*2/16)+255)/256,256,0,stream>>>(
      (uint4*)xh_all, (int)((size_t)Tn*Bn*3072*2/16));
  k_emb_all<<<Tn*Bn,256,0,stream>>>(caps_s, emb_w, xh_all);

  // h0/c0: [128,1024] = mean_bf @ [h0_w;c0_w]^T
  k_mfma_gemm<0,false><<<dim3(16,2),256,0,stream>>>(
      mean_bf, h0c0_bf, hc_b, hc, Bn, 1024, ENCn, 1024, nullptr, 0, 0, nullptr);
  k_h2bf<<<Bn,512,0,stream>>>(hc, h, c, h_bf, xh_all);

  // att1 (bf16 out) = enc_bf @ ea_w^T, XCD-swizzled grid
  k_mfma_gemm<1,true><<<dim3(392*8),256,0,stream>>>(
      enc_bf, ea_bf, ea_b, att1, Bn*Pn, An, ENCn, An, nullptr, 0, 0, nullptr);

  for (int t = 0; t < Tn; ++t) {
    unsigned short* xh_t = xh_all + (size_t)t*Bn*3072;
    // att2|gpre = h @ [da_w;gate_w]^T : [128,2560]
    k_mfma_gemm<0,false><<<dim3(40,2),256,0,stream>>>(
        h_bf, dg_bf, dg_b, att2g, Bn, 2560, Dn, 2560, declen_i, t, 0, nullptr);
    k_e_softmax<<<Bn,256,0,stream>>>(att1, att2g, fa_w, fa_b, alpha, out_alph, declen_i, t);
    k_awe_gate<<<dim3(ENCn/256,Bn),256,0,stream>>>(enc_bf, alpha, att2g, xh_t, declen_i, t);
    // gates = [emb|awe|h] @ [Wih|Whh]^T : [128,2048]
    k_mfma_gemm<0,false><<<dim3(32,2),256,0,stream>>>(
        xh_t, wcat_bf, bsum, gates, Bn, 2048, 3072, 2048, declen_i, t, 0, nullptr);
    k_lstm<<<Bn,512,0,stream>>>(gates, c, h, h_bf, xh_all, declen_i, t);
    // pred[:,t,:] = active ? h @ lin_w^T + lin_b : 0
    k_mfma_gemm<0,false><<<dim3((Vn+63)/64,2),256,0,stream>>>(
        h_bf, lin_bf, lin_b, out_pred + (size_t)t*Vn, Bn, Vn, Dn, (size_t)Tn*Vn,
        declen_i, t, 1, declen_i);
  }
}

// Round 4
// 2153.070 us; speedup vs baseline: 5.2704x; 1.0407x over previous
//
#include <hip/hip_runtime.h>
#include <hip/hip_bf16.h>
#include <math.h>

#define Bn 128
#define Pn 196
#define ENCn 2048
#define Dn 512
#define An 512
#define EDn 512
#define Vn 10000
#define Ln 20
#define Tn 19

typedef short v8s __attribute__((ext_vector_type(8)));
typedef short v4s __attribute__((ext_vector_type(4)));
typedef float v4f __attribute__((ext_vector_type(4)));

__device__ __forceinline__ float sigf(float x){ return 1.f/(1.f+__expf(-x)); }
__device__ __forceinline__ unsigned short f2bf(float f){
  unsigned u = __float_as_uint(f);
  return (unsigned short)((u + 0x7FFFu + ((u>>16)&1u)) >> 16);
}
__device__ __forceinline__ float bf2f(unsigned short h){
  return __uint_as_float(((unsigned)h)<<16);
}

// ---------------- setup kernels ----------------

__global__ void k_order(const int* __restrict__ caption_len,
                        const int* __restrict__ captions,
                        int* __restrict__ order_i, int* __restrict__ declen_i,
                        int* __restrict__ caps_s,
                        float* __restrict__ out_caps, float* __restrict__ out_declen,
                        float* __restrict__ out_order)
{
  __shared__ int lens[Bn];
  int b = threadIdx.x;
  lens[b] = caption_len[b];
  __syncthreads();
  int lb = lens[b];
  int r = 0;
  for (int j = 0; j < Bn; ++j) {
    int lj = lens[j];
    r += (int)((lj > lb) || (lj == lb && j < b));
  }
  order_i[r] = b;
  declen_i[r] = lb - 1;
  out_order[r] = (float)b;
  out_declen[r] = (float)(lb - 1);
  for (int t = 0; t < Ln; ++t) {
    int cv = captions[b*Ln + t];
    caps_s[r*Ln + t] = cv;
    out_caps[r*Ln + t] = (float)cv;
  }
}

// bsum reordered to (d*4+g); dg_b / hc_b plain concat
__global__ void k_setup_bias(const float* __restrict__ bih, const float* __restrict__ bhh,
                             const float* __restrict__ da_b, const float* __restrict__ gate_b,
                             const float* __restrict__ h0_b, const float* __restrict__ c0_b,
                             float* __restrict__ bsum_r, float* __restrict__ dg_b,
                             float* __restrict__ hc_b)
{
  int i = blockIdx.x*256 + threadIdx.x;
  if (i < 2048) {
    int d = i >> 2, g = i & 3;
    bsum_r[i] = bih[g*512+d] + bhh[g*512+d];
  }
  if (i < 2560) dg_b[i] = (i < 512) ? da_b[i] : gate_b[i-512];
  if (i < 1024) hc_b[i] = (i < 512) ? h0_b[i] : c0_b[i-512];
}

__global__ void k_cvt(const float* __restrict__ src, unsigned short* __restrict__ dst, int n)
{
  int i = (blockIdx.x*256 + threadIdx.x)*4;
  if (i < n) {
    float4 v = *(const float4*)(src + i);
    dst[i+0]=f2bf(v.x); dst[i+1]=f2bf(v.y); dst[i+2]=f2bf(v.z); dst[i+3]=f2bf(v.w);
  }
}

// wcat_r[d*4+g][3072] = [Wih | Whh][g*512+d][:] in bf16 (gate-interleaved rows)
__global__ void k_wcat(const float* __restrict__ Wih, const float* __restrict__ Whh,
                       unsigned short* __restrict__ dst)
{
  int i = (blockIdx.x*256 + threadIdx.x)*4;
  if (i >= 2048*3072) return;
  int rp = i/3072, j = i - rp*3072;
  int d = rp >> 2, g = rp & 3;
  int r = g*512 + d;
  const float* s = (j < 2560) ? (Wih + (size_t)r*2560 + j) : (Whh + (size_t)r*512 + (j-2560));
  float4 v = *(const float4*)s;
  dst[i+0]=f2bf(v.x); dst[i+1]=f2bf(v.y); dst[i+2]=f2bf(v.z); dst[i+3]=f2bf(v.w);
}

// sorted gather + f32->bf16: enc_bf[b_sorted][p][e]
__global__ void k_cvt_enc(const float* __restrict__ enc, const int* __restrict__ order_i,
                          unsigned short* __restrict__ dst)
{
  int id = blockIdx.x;               // b*196+p
  int b = id / Pn, p = id - b*Pn;
  const float* src = enc + ((size_t)order_i[b]*Pn + p)*ENCn;
  unsigned short* d = dst + (size_t)id*ENCn;
  int i = threadIdx.x*8;
  float4 v0 = *(const float4*)(src+i), v1 = *(const float4*)(src+i+4);
  d[i+0]=f2bf(v0.x); d[i+1]=f2bf(v0.y); d[i+2]=f2bf(v0.z); d[i+3]=f2bf(v0.w);
  d[i+4]=f2bf(v1.x); d[i+5]=f2bf(v1.y); d[i+6]=f2bf(v1.z); d[i+7]=f2bf(v1.w);
}

__global__ void k_mean(const unsigned short* __restrict__ enc_bf,
                       unsigned short* __restrict__ mean_bf)
{
  int b = blockIdx.x;
  const unsigned short* eb = enc_bf + (size_t)b*Pn*ENCn;
  for (int e = threadIdx.x; e < ENCn; e += 256) {
    float s = 0.f;
    for (int p = 0; p < Pn; ++p) s += bf2f(eb[(size_t)p*ENCn + e]);
    mean_bf[b*ENCn + e] = f2bf(s * (1.f/196.f));
  }
}

__global__ void k_zero(uint4* __restrict__ p, int n)
{
  int i = blockIdx.x*256 + threadIdx.x;
  if (i < n) p[i] = uint4{0,0,0,0};
}

__global__ void k_emb_all(const int* __restrict__ caps_s, const float* __restrict__ emb_w,
                          unsigned short* __restrict__ xh_all)
{
  int id = blockIdx.x; int t = id >> 7, b = id & 127;
  int tok = caps_s[b*Ln + t];
  const float* src = emb_w + (size_t)tok*EDn;
  unsigned short* d = xh_all + ((size_t)t*Bn + b)*3072;
  int i = threadIdx.x*2;
  float2 v = *(const float2*)(src+i);
  d[i] = f2bf(v.x); d[i+1] = f2bf(v.y);
}

__global__ void k_h2bf(const float* __restrict__ hc, float* __restrict__ c,
                       unsigned short* __restrict__ h_bf, unsigned short* __restrict__ xh_all)
{
  int b = blockIdx.x, d = threadIdx.x;
  float hv = hc[b*1024 + d];
  float cv = hc[b*1024 + 512 + d];
  c[b*Dn + d] = cv;
  unsigned short hb = f2bf(hv);
  h_bf[b*Dn + d] = hb;
  xh_all[(size_t)b*3072 + 2560 + d] = hb;
}

// ---------------- bf16 MFMA GEMM: C[M,N] = A[M,K] @ B[N,K]^T (+bias) ----------------
// MODE 0: grid (N/64, M/64); actlen tile-skip. MODE 1: att1 XCD swizzle.
template<int MODE, bool OUT_BF16>
__global__ __launch_bounds__(256) void k_mfma_gemm(
    const unsigned short* __restrict__ Aw, const unsigned short* __restrict__ Bw,
    const float* __restrict__ bias, void* __restrict__ Cp,
    int M, int N, int K, size_t ldc,
    const int* __restrict__ actlen, int t)
{
  __shared__ unsigned short smA[2][4096];
  __shared__ unsigned short smB[2][4096];
  const int tid = threadIdx.x;
  int bm0, bn0;
  if constexpr (MODE == 1) {
    int id = blockIdx.x;
    int xcd = id & 7, j = id >> 3;
    int g = j >> 6, rem = j & 63;
    int panel, col;
    if (g < 6) { panel = xcd*49 + g*8 + (rem & 7); col = rem >> 3; }
    else       { panel = xcd*49 + 48;              col = rem; }
    bm0 = panel*64; bn0 = col*64;
  } else {
    bm0 = blockIdx.y*64; bn0 = blockIdx.x*64;
  }

  if (MODE == 0 && actlen && actlen[bm0] <= t) return;

  const int lane = tid & 63, w = tid >> 6;
  const int wr = w >> 1, wc = w & 1;
  const int lrow = lane & 15, kq = lane >> 4;

  v4f acc[2][2];
  #pragma unroll
  for (int i=0;i<2;++i)
    #pragma unroll
    for (int j=0;j<2;++j) acc[i][j] = (v4f)0.f;

  const int nt = K >> 6;

  auto stage = [&](int buf, int k0) {
    #pragma unroll
    for (int it = 0; it < 2; ++it) {
      int s = it*256 + tid;
      int row = s >> 3;
      int kb  = (s & 7) ^ (row & 7);
      {
        int gr = bm0 + row;
        const v8s v = *(const v8s*)(Aw + (size_t)gr*K + k0 + kb*8);
        *(v8s*)&smA[buf][s*8] = v;
      }
      {
        int gn = bn0 + row; if (gn >= N) gn = N-1;
        const v8s v = *(const v8s*)(Bw + (size_t)gn*K + k0 + kb*8);
        *(v8s*)&smB[buf][s*8] = v;
      }
    }
  };

  auto compute = [&](int buf) {
    #pragma unroll
    for (int kc = 0; kc < 2; ++kc) {
      v8s aF[2], bF[2];
      #pragma unroll
      for (int mi = 0; mi < 2; ++mi) {
        int row = wr*32 + mi*16 + lrow;
        int kb = kc*4 + kq;
        aF[mi] = *(const v8s*)&smA[buf][row*64 + ((kb ^ (row&7))<<3)];
      }
      #pragma unroll
      for (int ni = 0; ni < 2; ++ni) {
        int row = wc*32 + ni*16 + lrow;
        int kb = kc*4 + kq;
        bF[ni] = *(const v8s*)&smB[buf][row*64 + ((kb ^ (row&7))<<3)];
      }
      #pragma unroll
      for (int mi = 0; mi < 2; ++mi)
        #pragma unroll
        for (int ni = 0; ni < 2; ++ni)
          acc[mi][ni] = __builtin_amdgcn_mfma_f32_16x16x32_bf16(aF[mi], bF[ni], acc[mi][ni], 0, 0, 0);
    }
  };

  stage(0, 0);
  __syncthreads();
  for (int tk = 0; tk < nt; ++tk) {
    if (tk + 1 < nt) stage((tk+1)&1, (tk+1)<<6);
    compute(tk&1);
    __syncthreads();
  }

  #pragma unroll
  for (int mi=0; mi<2; ++mi)
    #pragma unroll
    for (int ni=0; ni<2; ++ni) {
      #pragma unroll
      for (int r=0; r<4; ++r) {
        int m = bm0 + wr*32 + mi*16 + kq*4 + r;
        int n = bn0 + wc*32 + ni*16 + lrow;
        if (m < M && n < N) {
          float v = acc[mi][ni][r] + (bias ? bias[n] : 0.f);
          if constexpr (OUT_BF16) ((unsigned short*)Cp)[(size_t)m*ldc + n] = f2bf(v);
          else ((float*)Cp)[(size_t)m*ldc + n] = v;
        }
      }
    }
}

// ---------------- gates GEMM + LSTM epilogue ----------------
// A = xh_t [128][3072], B = wcat_r [2048][3072] (row = d*4+g), grid (32,2).
__global__ __launch_bounds__(256) void k_gates_lstm(
    const unsigned short* __restrict__ Aw, const unsigned short* __restrict__ Bw,
    const float* __restrict__ bias,
    float* __restrict__ c, unsigned short* __restrict__ h_bf,
    unsigned short* __restrict__ h_all, unsigned short* __restrict__ xh_all,
    const int* __restrict__ declen_i, int t)
{
  __shared__ unsigned short smA[2][4096];
  __shared__ unsigned short smB[2][4096];
  __shared__ float smC[64][65];
  const int tid = threadIdx.x;
  const int bm0 = blockIdx.y*64, bn0 = blockIdx.x*64;
  if (declen_i[bm0] <= t) return;

  const int lane = tid & 63, w = tid >> 6;
  const int wr = w >> 1, wc = w & 1;
  const int lrow = lane & 15, kq = lane >> 4;
  const int K = 3072;

  v4f acc[2][2];
  #pragma unroll
  for (int i=0;i<2;++i)
    #pragma unroll
    for (int j=0;j<2;++j) acc[i][j] = (v4f)0.f;

  auto stage = [&](int buf, int k0) {
    #pragma unroll
    for (int it = 0; it < 2; ++it) {
      int s = it*256 + tid;
      int row = s >> 3;
      int kb  = (s & 7) ^ (row & 7);
      {
        const v8s v = *(const v8s*)(Aw + (size_t)(bm0+row)*K + k0 + kb*8);
        *(v8s*)&smA[buf][s*8] = v;
      }
      {
        const v8s v = *(const v8s*)(Bw + (size_t)(bn0+row)*K + k0 + kb*8);
        *(v8s*)&smB[buf][s*8] = v;
      }
    }
  };
  auto compute = [&](int buf) {
    #pragma unroll
    for (int kc = 0; kc < 2; ++kc) {
      v8s aF[2], bF[2];
      #pragma unroll
      for (int mi = 0; mi < 2; ++mi) {
        int row = wr*32 + mi*16 + lrow;
        int kb = kc*4 + kq;
        aF[mi] = *(const v8s*)&smA[buf][row*64 + ((kb ^ (row&7))<<3)];
      }
      #pragma unroll
      for (int ni = 0; ni < 2; ++ni) {
        int row = wc*32 + ni*16 + lrow;
        int kb = kc*4 + kq;
        bF[ni] = *(const v8s*)&smB[buf][row*64 + ((kb ^ (row&7))<<3)];
      }
      #pragma unroll
      for (int mi = 0; mi < 2; ++mi)
        #pragma unroll
        for (int ni = 0; ni < 2; ++ni)
          acc[mi][ni] = __builtin_amdgcn_mfma_f32_16x16x32_bf16(aF[mi], bF[ni], acc[mi][ni], 0, 0, 0);
    }
  };

  stage(0, 0);
  __syncthreads();
  const int nt = K >> 6;
  for (int tk = 0; tk < nt; ++tk) {
    if (tk + 1 < nt) stage((tk+1)&1, (tk+1)<<6);
    compute(tk&1);
    __syncthreads();
  }

  // stash tile (with bias) to LDS
  #pragma unroll
  for (int mi=0; mi<2; ++mi)
    #pragma unroll
    for (int ni=0; ni<2; ++ni)
      #pragma unroll
      for (int r=0; r<4; ++r) {
        int ml = wr*32 + mi*16 + kq*4 + r;
        int nl = wc*32 + ni*16 + lrow;
        smC[ml][nl] = acc[mi][ni][r] + bias[bn0 + nl];
      }
  __syncthreads();

  // LSTM elementwise: tile = 64 b-rows x 16 d-values (4 gates each)
  for (int idx = tid; idx < 1024; idx += 256) {
    int ml = idx >> 4, dl = idx & 15;
    int b = bm0 + ml;
    if (t < declen_i[b]) {
      int dg = (bn0 >> 2) + dl;
      float gi = smC[ml][dl*4+0];
      float gf = smC[ml][dl*4+1];
      float gg = smC[ml][dl*4+2];
      float go = smC[ml][dl*4+3];
      float cv = c[b*Dn + dg];
      float cn = sigf(gf)*cv + sigf(gi)*tanhf(gg);
      float hn = sigf(go)*tanhf(cn);
      c[b*Dn + dg] = cn;
      unsigned short hb = f2bf(hn);
      h_bf[b*Dn + dg] = hb;
      h_all[((size_t)t*Bn + b)*Dn + dg] = hb;
      if (t + 1 < Tn)
        xh_all[((size_t)(t+1)*Bn + b)*3072 + 2560 + dg] = hb;
    }
  }
}

// ---------------- batched pred GEMM (all t at once) ----------------
// A = h_all [2432][512] (m = t*128+b), B = lin_bf [10000][512], grid (157,38).
__global__ __launch_bounds__(256) void k_pred(
    const unsigned short* __restrict__ Aw, const unsigned short* __restrict__ Bw,
    const float* __restrict__ bias, float* __restrict__ out_pred,
    const int* __restrict__ declen_i)
{
  __shared__ unsigned short smA[2][4096];
  __shared__ unsigned short smB[2][4096];
  const int tid = threadIdx.x;
  const int bm0 = blockIdx.y*64, bn0 = blockIdx.x*64;
  const int t0 = bm0 >> 7, b0 = bm0 & 127;

  if (declen_i[b0] <= t0) {
    // whole tile inactive -> zeros
    for (int i = tid; i < 4096; i += 256) {
      int ml = i >> 6, nl = i & 63;
      int n = bn0 + nl;
      if (n < Vn) {
        int m = bm0 + ml;
        out_pred[((size_t)(m & 127)*Tn + (m >> 7))*Vn + n] = 0.f;
      }
    }
    return;
  }

  const int lane = tid & 63, w = tid >> 6;
  const int wr = w >> 1, wc = w & 1;
  const int lrow = lane & 15, kq = lane >> 4;
  const int K = 512;

  v4f acc[2][2];
  #pragma unroll
  for (int i=0;i<2;++i)
    #pragma unroll
    for (int j=0;j<2;++j) acc[i][j] = (v4f)0.f;

  auto stage = [&](int buf, int k0) {
    #pragma unroll
    for (int it = 0; it < 2; ++it) {
      int s = it*256 + tid;
      int row = s >> 3;
      int kb  = (s & 7) ^ (row & 7);
      {
        const v8s v = *(const v8s*)(Aw + (size_t)(bm0+row)*K + k0 + kb*8);
        *(v8s*)&smA[buf][s*8] = v;
      }
      {
        int gn = bn0 + row; if (gn >= Vn) gn = Vn-1;
        const v8s v = *(const v8s*)(Bw + (size_t)gn*K + k0 + kb*8);
        *(v8s*)&smB[buf][s*8] = v;
      }
    }
  };
  auto compute = [&](int buf) {
    #pragma unroll
    for (int kc = 0; kc < 2; ++kc) {
      v8s aF[2], bF[2];
      #pragma unroll
      for (int mi = 0; mi < 2; ++mi) {
        int row = wr*32 + mi*16 + lrow;
        int kb = kc*4 + kq;
        aF[mi] = *(const v8s*)&smA[buf][row*64 + ((kb ^ (row&7))<<3)];
      }
      #pragma unroll
      for (int ni = 0; ni < 2; ++ni) {
        int row = wc*32 + ni*16 + lrow;
        int kb = kc*4 + kq;
        bF[ni] = *(const v8s*)&smB[buf][row*64 + ((kb ^ (row&7))<<3)];
      }
      #pragma unroll
      for (int mi = 0; mi < 2; ++mi)
        #pragma unroll
        for (int ni = 0; ni < 2; ++ni)
          acc[mi][ni] = __builtin_amdgcn_mfma_f32_16x16x32_bf16(aF[mi], bF[ni], acc[mi][ni], 0, 0, 0);
    }
  };

  stage(0, 0);
  __syncthreads();
  const int nt = K >> 6;
  for (int tk = 0; tk < nt; ++tk) {
    if (tk + 1 < nt) stage((tk+1)&1, (tk+1)<<6);
    compute(tk&1);
    __syncthreads();
  }

  #pragma unroll
  for (int mi=0; mi<2; ++mi)
    #pragma unroll
    for (int ni=0; ni<2; ++ni)
      #pragma unroll
      for (int r=0; r<4; ++r) {
        int m = bm0 + wr*32 + mi*16 + kq*4 + r;
        int n = bn0 + wc*32 + ni*16 + lrow;
        if (n < Vn) {
          int b = m & 127, tt = m >> 7;
          float v = (tt < declen_i[b]) ? (acc[mi][ni][r] + bias[n]) : 0.f;
          out_pred[((size_t)b*Tn + tt)*Vn + n] = v;
        }
      }
}

// ---------------- fused e-dot + softmax + awe + gate ----------------
// grid (2, 128): y = b, x = e-half (1024 each). alpha lives in LDS.
__global__ __launch_bounds__(256) void k_attn_step(
    const unsigned short* __restrict__ att1, const unsigned short* __restrict__ enc_bf,
    const float* __restrict__ att2g,
    const float* __restrict__ fa_w, const float* __restrict__ fa_b,
    float* __restrict__ out_alph, unsigned short* __restrict__ xh_t,
    const int* __restrict__ declen_i, int t)
{
  int b = blockIdx.y;
  int half = blockIdx.x;
  int tid = threadIdx.x;
  if (t >= declen_i[b]) {
    if (half == 0)
      for (int p = tid; p < Pn; p += 256)
        out_alph[(size_t)b*Tn*Pn + (size_t)t*Pn + p] = 0.f;
    return;
  }
  __shared__ float a2s[An];
  __shared__ float fws[An];
  __shared__ float es[Pn];
  __shared__ float wred[4];
  __shared__ float wsum[4];
  for (int i = tid; i < An; i += 256) { a2s[i] = att2g[(size_t)b*2560 + i]; fws[i] = fa_w[i]; }
  __syncthreads();
  int lane = tid & 63, w = tid >> 6;
  const unsigned short* a1b = att1 + (size_t)b*Pn*An;
  float fb = fa_b[0];
  for (int p = w; p < Pn; p += 4) {
    const v8s vv = *(const v8s*)(a1b + (size_t)p*An + lane*8);
    float s = 0.f;
    #pragma unroll
    for (int j = 0; j < 8; ++j) {
      int a = lane*8 + j;
      float v = bf2f((unsigned short)vv[j]) + a2s[a];
      s += fmaxf(v, 0.f) * fws[a];
    }
    for (int off = 32; off; off >>= 1) s += __shfl_down(s, off);
    if (lane == 0) es[p] = s + fb;
  }
  __syncthreads();
  float m = -1e30f;
  for (int p = tid; p < Pn; p += 256) m = fmaxf(m, es[p]);
  for (int off = 32; off; off >>= 1) m = fmaxf(m, __shfl_down(m, off));
  if (lane == 0) wred[w] = m;
  __syncthreads();
  m = fmaxf(fmaxf(wred[0], wred[1]), fmaxf(wred[2], wred[3]));
  float s = 0.f;
  for (int p = tid; p < Pn; p += 256) { float ev = __expf(es[p] - m); es[p] = ev; s += ev; }
  for (int off = 32; off; off >>= 1) s += __shfl_down(s, off);
  if (lane == 0) wsum[w] = s;
  __syncthreads();
  s = wsum[0] + wsum[1] + wsum[2] + wsum[3];
  float inv = 1.f / s;
  for (int p = tid; p < Pn; p += 256) es[p] *= inv;
  __syncthreads();
  if (half == 0)
    for (int p = tid; p < Pn; p += 256)
      out_alph[(size_t)b*Tn*Pn + (size_t)t*Pn + p] = es[p];

  // awe + gate for this e-half: 1024 elems, 4 per thread
  int eg = half*1024 + tid*4;
  const unsigned short* eb = enc_bf + (size_t)b*Pn*ENCn + eg;
  float s0=0.f, s1=0.f, s2=0.f, s3=0.f;
  #pragma unroll 4
  for (int p = 0; p < Pn; ++p) {
    v4s v = *(const v4s*)(eb + (size_t)p*ENCn);
    float a = es[p];
    s0 += a*bf2f((unsigned short)v[0]);
    s1 += a*bf2f((unsigned short)v[1]);
    s2 += a*bf2f((unsigned short)v[2]);
    s3 += a*bf2f((unsigned short)v[3]);
  }
  float4 gp = *(const float4*)(att2g + (size_t)b*2560 + 512 + eg);
  unsigned short* d = xh_t + (size_t)b*3072 + 512 + eg;
  d[0] = f2bf(sigf(gp.x)*s0);
  d[1] = f2bf(sigf(gp.y)*s1);
  d[2] = f2bf(sigf(gp.z)*s2);
  d[3] = f2bf(sigf(gp.w)*s3);
}

// ---------------- launch ----------------

extern "C" void kernel_launch(void* const* d_in, const int* in_sizes, int n_in,
                              void* d_out, int out_size, void* d_ws, size_t ws_size,
                              hipStream_t stream)
{
  const float* enc     = (const float*)d_in[0];
  const int*   captions= (const int*)d_in[1];
  const int*   cap_len = (const int*)d_in[2];
  const float* emb_w   = (const float*)d_in[3];
  const float* Wih     = (const float*)d_in[4];
  const float* Whh     = (const float*)d_in[5];
  const float* bih     = (const float*)d_in[6];
  const float* bhh     = (const float*)d_in[7];
  const float* h0_w    = (const float*)d_in[8];
  const float* h0_b    = (const float*)d_in[9];
  const float* c0_w    = (const float*)d_in[10];
  const float* c0_b    = (const float*)d_in[11];
  const float* gate_w  = (const float*)d_in[12];
  const float* gate_b  = (const float*)d_in[13];
  const float* lin_w   = (const float*)d_in[14];
  const float* lin_b   = (const float*)d_in[15];
  const float* ea_w    = (const float*)d_in[16];
  const float* ea_b    = (const float*)d_in[17];
  const float* da_w    = (const float*)d_in[18];
  const float* da_b    = (const float*)d_in[19];
  const float* fa_w    = (const float*)d_in[20];
  const float* fa_b    = (const float*)d_in[21];

  float* out = (float*)d_out;
  float* out_pred   = out;                               // [128][19][10000]
  float* out_caps   = out + (size_t)Bn*Tn*Vn;            // [128][20]
  float* out_declen = out_caps + Bn*Ln;                  // [128]
  float* out_alph   = out_declen + Bn;                   // [128][19][196]
  float* out_order  = out_alph + (size_t)Bn*Tn*Pn;       // [128]

  char* wp = (char*)d_ws;
  auto alloc = [&](size_t bytes)->void* {
    void* p = (void*)wp; wp += (bytes + 255) & ~(size_t)255; return p;
  };
  int*   order_i  = (int*)alloc(Bn*4);
  int*   declen_i = (int*)alloc(Bn*4);
  int*   caps_s   = (int*)alloc(Bn*Ln*4);
  unsigned short* enc_bf  = (unsigned short*)alloc((size_t)Bn*Pn*ENCn*2);  // 102.8 MB
  unsigned short* mean_bf = (unsigned short*)alloc((size_t)Bn*ENCn*2);
  float* hc       = (float*)alloc((size_t)Bn*1024*4);
  float* c        = (float*)alloc((size_t)Bn*Dn*4);
  unsigned short* h_bf   = (unsigned short*)alloc((size_t)Bn*Dn*2);
  unsigned short* h_all  = (unsigned short*)alloc((size_t)Tn*Bn*Dn*2);     // 2.5 MB
  unsigned short* xh_all = (unsigned short*)alloc((size_t)Tn*Bn*3072*2);   // 14.9 MB
  unsigned short* att1   = (unsigned short*)alloc((size_t)Bn*Pn*An*2);     // 25.7 MB
  float* att2g    = (float*)alloc((size_t)Bn*2560*4);
  unsigned short* ea_bf   = (unsigned short*)alloc((size_t)An*ENCn*2);
  unsigned short* lin_bf  = (unsigned short*)alloc((size_t)Vn*Dn*2);
  unsigned short* h0c0_bf = (unsigned short*)alloc((size_t)1024*ENCn*2);
  unsigned short* dg_bf   = (unsigned short*)alloc((size_t)2560*Dn*2);
  unsigned short* wcat_bf = (unsigned short*)alloc((size_t)2048*3072*2);
  float* bsum = (float*)alloc(2048*4);
  float* dg_b = (float*)alloc(2560*4);
  float* hc_b = (float*)alloc(1024*4);

  // ---- setup ----
  k_order<<<1,128,0,stream>>>(cap_len, captions, order_i, declen_i, caps_s,
                              out_caps, out_declen, out_order);
  k_setup_bias<<<10,256,0,stream>>>(bih, bhh, da_b, gate_b, h0_b, c0_b, bsum, dg_b, hc_b);
  k_cvt<<<(An*ENCn/4+255)/256,256,0,stream>>>(ea_w, ea_bf, An*ENCn);
  k_cvt<<<(Vn*Dn/4+255)/256,256,0,stream>>>(lin_w, lin_bf, Vn*Dn);
  k_cvt<<<(Dn*ENCn/4+255)/256,256,0,stream>>>(h0_w, h0c0_bf, Dn*ENCn);
  k_cvt<<<(Dn*ENCn/4+255)/256,256,0,stream>>>(c0_w, h0c0_bf + (size_t)512*ENCn, Dn*ENCn);
  k_cvt<<<(An*Dn/4+255)/256,256,0,stream>>>(da_w, dg_bf, An*Dn);
  k_cvt<<<(ENCn*Dn/4+255)/256,256,0,stream>>>(gate_w, dg_bf + (size_t)512*Dn, ENCn*Dn);
  k_wcat<<<(2048*3072/4+255)/256,256,0,stream>>>(Wih, Whh, wcat_bf);
  k_cvt_enc<<<Bn*Pn,256,0,stream>>>(enc, order_i, enc_bf);
  k_mean<<<Bn,256,0,stream>>>(enc_bf, mean_bf);
  k_zero<<<((int)((size_t)Tn*Bn*3072*2/16)+255)/256,256,0,stream>>>(
      (uint4*)xh_all, (int)((size_t)Tn*Bn*3072*2/16));
  k_emb_all<<<Tn*Bn,256,0,stream>>>(caps_s, emb_w, xh_all);

  // h0/c0
  k_mfma_gemm<0,false><<<dim3(16,2),256,0,stream>>>(
      mean_bf, h0c0_bf, hc_b, hc, Bn, 1024, ENCn, 1024, nullptr, 0);
  k_h2bf<<<Bn,512,0,stream>>>(hc, c, h_bf, xh_all);

  // att1 = enc_bf @ ea_w^T (bf16 out), XCD-swizzled
  k_mfma_gemm<1,true><<<dim3(392*8),256,0,stream>>>(
      enc_bf, ea_bf, ea_b, att1, Bn*Pn, An, ENCn, An, nullptr, 0);

  for (int t = 0; t < Tn; ++t) {
    unsigned short* xh_t = xh_all + (size_t)t*Bn*3072;
    // att2|gpre = h @ [da_w;gate_w]^T : [128,2560]
    k_mfma_gemm<0,false><<<dim3(40,2),256,0,stream>>>(
        h_bf, dg_bf, dg_b, att2g, Bn, 2560, Dn, 2560, declen_i, t);
    // e-dot + softmax + awe + gate
    k_attn_step<<<dim3(2,Bn),256,0,stream>>>(
        att1, enc_bf, att2g, fa_w, fa_b, out_alph, xh_t, declen_i, t);
    // gates GEMM + LSTM epilogue
    k_gates_lstm<<<dim3(32,2),256,0,stream>>>(
        xh_t, wcat_bf, bsum, c, h_bf, h_all, xh_all, declen_i, t);
  }

  // batched pred over all t
  k_pred<<<dim3((Vn+63)/64, (Tn*Bn)/64),256,0,stream>>>(
      h_all, lin_bf, lin_b, out_pred, declen_i);
}